// Round 4
// baseline (546.267 us; speedup 1.0000x reference)
//
#include <hip/hip_runtime.h>
#include <hip/hip_bf16.h>

typedef unsigned short u16;
typedef __attribute__((ext_vector_type(8))) short short8;
typedef __attribute__((ext_vector_type(4))) float f32x4;

#define T_STEPS 10
#define NB 8
#define HH 64
#define WW 64
#define FF 64
#define NGATE 256
#define HP 66
#define PIX (NB*HH*WW)          // 32768

__device__ __forceinline__ u16 f2bf(float f) {
    unsigned u = __float_as_uint(f);
    u += 0x7FFF + ((u >> 16) & 1);   // round-to-nearest-even
    return (u16)(u >> 16);
}
__device__ __forceinline__ float hsig(float x) {
    return fminf(fmaxf(0.2f * x + 0.5f, 0.0f), 1.0f);
}
__device__ __forceinline__ float ftanh(float x) {
    float e = __expf(2.0f * x);
    return 1.0f - 2.0f / (e + 1.0f);
}
__device__ __forceinline__ void gll16(const void* g, void* l) {
    __builtin_amdgcn_global_load_lds(
        (const __attribute__((address_space(1))) unsigned*)g,
        (__attribute__((address_space(3))) unsigned*)l, 16, 0, 0);
}

// Build B in MFMA-fragment-stream order, bf16:
//   stream[kc][fq][ks][g][lane][e]; value = W[kc*64+ks*32+quad*8+e][g*64+fq*16+l15]
__global__ void wtrans_kernel(const float* __restrict__ W0,
                              const float* __restrict__ W1,
                              u16* __restrict__ BS, int K) {
    int total = (K >> 6) << 14;
    for (int o = blockIdx.x * blockDim.x + threadIdx.x; o < total;
         o += gridDim.x * blockDim.x) {
        int e = o & 7, lane = (o >> 3) & 63, g = (o >> 9) & 3;
        int ks = (o >> 11) & 1, fq = (o >> 12) & 3, kc = o >> 14;
        int quad = lane >> 4, l15 = lane & 15;
        int n = g * 64 + fq * 16 + l15;
        int k = kc * 64 + ks * 32 + quad * 8 + e;
        float v = (k < 576) ? W0[k * NGATE + n] : W1[(k - 576) * NGATE + n];
        BS[o] = f2bf(v);
    }
}

// Stage one kc-chunk of the A tile (128 pixels = 2 rows x 64 cols, 64 ch)
// into LDS: 1024 16B-chunks; chunk q holds px=q>>3, ch-block (q&7)^(px&7).
__device__ __forceinline__ void stageA(const u16* __restrict__ h0_prev,
                                       const u16* __restrict__ h1_prev,
                                       int kcs, int b, int y0, int tid,
                                       const int pxA[4], const int cbA[4],
                                       u16* lbase) {
    int tau = (kcs < 9) ? kcs : kcs - 9;
    const u16* src = (kcs < 9) ? h0_prev : h1_prev;
    int dy = tau / 3 - 1, dx = tau % 3 - 1;
#pragma unroll
    for (int i = 0; i < 4; ++i) {
        int px = pxA[i];
        int row = y0 + (px >> 6) + dy + 1;      // padded h row
        int col = (px & 63) + dx + 1;           // padded h col
        const u16* g = src + (((size_t)(b * HP + row)) * HP + col) * FF
                     + cbA[i] * 8;
        gll16(g, lbase + (size_t)(tid + i * 256) * 8);
    }
}

// Fused dual-layer ConvLSTM tick; XCD-local batches (batch = blockIdx & 7).
// M=128 register blocking; 512 blocks = 2/CU (1 role-0 + 1 role-1 per CU).
// Counted-vmcnt schedule (r3 post-mortem: the old issue order made every
// bF1-use wait an effective vmcnt(0) drain — in-order vmcnt retirement).
// Per iteration I:
//   issue bF(I+1) x8  ->  s_waitcnt vmcnt(8)  ->  s_barrier
//   ->  issue gll(I+2) x4 (slot (I+2)%3, safe: all waves past barrier)
//   ->  compute 64 MFMAs (lgkm waits only).
// vmcnt(8) keeps the 8 fresh B loads in flight and forces exactly bF(I)
// and gll(I+1), both issued a FULL iteration earlier (latency fully hidden).
// B regs ping-pong bFA/bFB via unroll-2 loop (no copies); dummy tail
// reloads keep the vmcnt population uniform (asm "memory" blocks CSE).
__global__ __launch_bounds__(256, 2)
void fused_step_kernel(const u16* __restrict__ h0_prev, u16* __restrict__ h0_new,
                       const u16* __restrict__ h1_prev, u16* __restrict__ h1_new,
                       const u16* __restrict__ B0S, const u16* __restrict__ B1S,
                       const float* __restrict__ x, const float* __restrict__ k0w,
                       const float* __restrict__ b0, const float* __restrict__ b1,
                       float* __restrict__ c0, float* __restrict__ c1,
                       float* __restrict__ oh0, float* __restrict__ oc0,
                       float* __restrict__ oh1, float* __restrict__ oc1,
                       int u) {
    int blk = blockIdx.x;
    int b = blk & 7;                 // batch == XCD (blockIdx % 8 round-robin)
    int k = blk >> 3;                // XCD-local index 0..63 (-> CU k%32)
    int role = (k >> 5) & 1;         // 0: layer-0 step u; 1: layer-1 step u-1
    int y0 = (k & 31) * 2;           // first of two image rows 0..62
    if (role == 0 && u >= T_STEPS) return;
    if (role == 1 && u == 0) return;

    __shared__ __align__(16) u16 sA3[3][8192];
    __shared__ float xs[4][WW + 2];

    int tid = threadIdx.x;
    int lane = tid & 63, fq = tid >> 6;
    int quad = lane >> 4, l15 = lane & 15;

    const u16* BS = role ? B1S : B0S;
    int nch = role ? 18 : 9;

    if (role == 0) {
        for (int i = tid; i < 4 * (WW + 2); i += 256) {
            int j = i / (WW + 2), xx = i - j * (WW + 2);
            int yy = y0 + j - 1, col = xx - 1;
            float v = 0.0f;
            if (yy >= 0 && yy < HH && col >= 0 && col < WW)
                v = x[(((size_t)b * T_STEPS + u) * HH + yy) * WW + col];
            xs[j][xx] = v;
        }
    }

    // Per-thread staging chunks.
    int pxA[4], cbA[4];
#pragma unroll
    for (int i = 0; i < 4; ++i) {
        int q = tid + i * 256;
        pxA[i] = q >> 3;
        cbA[i] = (q & 7) ^ (pxA[i] & 7);
    }

    f32x4 acc[8][4];
#pragma unroll
    for (int mt = 0; mt < 8; ++mt)
#pragma unroll
        for (int g = 0; g < 4; ++g)
            acc[mt][g] = (f32x4){0.f, 0.f, 0.f, 0.f};

    const u16* bbase = BS + (fq << 12) + lane * 8;   // + kc<<14 + ks<<11 + g<<9
    short8 bFA[8], bFB[8];
    int sx = l15 & 7;

    // ---- prologue ----
    stageA(h0_prev, h1_prev, 0, b, y0, tid, pxA, cbA, &sA3[0][0]);
#pragma unroll
    for (int g = 0; g < 4; ++g) {                    // bFA <- B(kc=0)
        bFA[g]     = *(const short8*)(bbase + (g << 9));
        bFA[4 + g] = *(const short8*)(bbase + (1 << 11) + (g << 9));
    }
    // forces gll(0) returned (keeps bFA's 8 in flight); barrier -> visible
    asm volatile("s_waitcnt vmcnt(8) lgkmcnt(0)\n\ts_barrier" ::: "memory");
    stageA(h0_prev, h1_prev, 1, b, y0, tid, pxA, cbA, &sA3[1][0]);

    int cur = 0;

#define BODY(I, BC, BN)                                                       \
    {                                                                         \
        int kn = ((I) + 1 < nch) ? (I) + 1 : nch - 1;                         \
        const u16* bpn = bbase + ((size_t)kn << 14);                          \
        _Pragma("unroll")                                                     \
        for (int g = 0; g < 4; ++g) {                                         \
            BN[g]     = *(const short8*)(bpn + (g << 9));                     \
            BN[4 + g] = *(const short8*)(bpn + (1 << 11) + (g << 9));         \
        }                                                                     \
        asm volatile("s_waitcnt vmcnt(8) lgkmcnt(0)\n\ts_barrier" ::: "memory"); \
        {                                                                     \
            int ksrc = ((I) + 2 < nch) ? (I) + 2 : (I);                       \
            int bdst = cur + 2; if (bdst >= 3) bdst -= 3;                     \
            stageA(h0_prev, h1_prev, ksrc, b, y0, tid, pxA, cbA,              \
                   &sA3[bdst][0]);                                            \
        }                                                                     \
        __builtin_amdgcn_s_setprio(1);                                        \
        _Pragma("unroll")                                                     \
        for (int ks = 0; ks < 2; ++ks) {                                      \
            _Pragma("unroll")                                                 \
            for (int mt = 0; mt < 8; ++mt) {                                  \
                int px = mt * 16 + l15;                                       \
                int chunk = px * 8 + ((ks * 4 + quad) ^ sx);                  \
                short8 a = *(const short8*)&sA3[cur][(size_t)chunk * 8];      \
                _Pragma("unroll")                                             \
                for (int g = 0; g < 4; ++g)                                   \
                    acc[mt][g] = __builtin_amdgcn_mfma_f32_16x16x32_bf16(     \
                        a, BC[ks * 4 + g], acc[mt][g], 0, 0, 0);              \
            }                                                                 \
        }                                                                     \
        __builtin_amdgcn_s_setprio(0);                                        \
        cur = (cur == 2) ? 0 : cur + 1;                                       \
    }

    for (int I = 0; I < nch; I += 2) {
        BODY(I, bFA, bFB);
        if (I + 1 < nch) BODY(I + 1, bFB, bFA);
    }
#undef BODY

    // ---- epilogue: LSTM gate update (lane-local: f = fq*16+l15) ----
    const float* bias = role ? b1 : b0;
    float* cbuf = role ? c1 : c0;
    u16* hout = role ? h1_new : h0_new;
    int wo = role ? (u == T_STEPS) : (u == T_STEPS - 1);
    float* outh = role ? oh1 : oh0;
    float* outc = role ? oc1 : oc0;

    int f = fq * 16 + l15;
    float bi = bias[f], bff = bias[64 + f], bg = bias[128 + f], bo = bias[192 + f];
    float wk[4][9];
    if (role == 0) {
#pragma unroll
        for (int g = 0; g < 4; ++g)
#pragma unroll
            for (int tau = 0; tau < 9; ++tau)
                wk[g][tau] = k0w[tau * NGATE + g * 64 + f];
    }
#pragma unroll
    for (int mt = 0; mt < 8; ++mt) {
#pragma unroll
        for (int r = 0; r < 4; ++r) {
            int pxl = mt * 16 + quad * 4 + r;       // 0..127 within A tile
            int rg = pxl >> 6, col = pxl & 63;      // local row, image col
            size_t p = ((size_t)(b * 64 + y0 + rg)) * 64 + col;  // global pixel
            float zi = acc[mt][0][r] + bi;
            float zf = acc[mt][1][r] + bff;
            float zg = acc[mt][2][r] + bg;
            float zo = acc[mt][3][r] + bo;
            if (role == 0) {   // fused layer-0 input conv, fp32 exact
#pragma unroll
                for (int tau = 0; tau < 9; ++tau) {
                    float xv = xs[rg + tau / 3][col + tau % 3];
                    zi += xv * wk[0][tau];
                    zf += xv * wk[1][tau];
                    zg += xv * wk[2][tau];
                    zo += xv * wk[3][tau];
                }
            }
            float cold = cbuf[p * FF + f];
            float cn = hsig(zf) * cold + hsig(zi) * ftanh(zg);
            float hn = hsig(zo) * ftanh(cn);
            cbuf[p * FF + f] = cn;
            hout[(((size_t)(b * HP + y0 + rg + 1)) * HP + (col + 1)) * FF + f]
                = f2bf(hn);
            if (wo) { outh[p * FF + f] = hn; outc[p * FF + f] = cn; }
        }
    }
}

extern "C" void kernel_launch(void* const* d_in, const int* in_sizes, int n_in,
                              void* d_out, int out_size, void* d_ws, size_t ws_size,
                              hipStream_t stream) {
    const float* x   = (const float*)d_in[0];
    const float* k0  = (const float*)d_in[1];
    const float* rk0 = (const float*)d_in[2];
    const float* b0  = (const float*)d_in[3];
    const float* k1  = (const float*)d_in[4];
    const float* rk1 = (const float*)d_in[5];
    const float* b1  = (const float*)d_in[6];
    float* out = (float*)d_out;

    char* ws = (char*)d_ws;
    const size_t HPAD_BYTES = (size_t)NB * HP * HP * FF * 2;  // 4,460,544
    const size_t C_BYTES    = (size_t)PIX * FF * 4;           // 8,388,608

    u16* h0p[2]; u16* h1p[2];
    h0p[0] = (u16*)(ws);
    h0p[1] = (u16*)(ws + HPAD_BYTES);
    h1p[0] = (u16*)(ws + 2 * HPAD_BYTES);
    h1p[1] = (u16*)(ws + 3 * HPAD_BYTES);
    float* c0 = (float*)(ws + 4 * HPAD_BYTES);
    float* c1 = (float*)(ws + 4 * HPAD_BYTES + C_BYTES);
    u16* B0S  = (u16*)(ws + 4 * HPAD_BYTES + 2 * C_BYTES);
    u16* B1S  = (u16*)(ws + 4 * HPAD_BYTES + 2 * C_BYTES + (size_t)9 * 16384 * 2);

    // Zero h (incl. halo == SAME padding) and c states; ws is poisoned 0xAA.
    hipMemsetAsync(ws, 0, 4 * HPAD_BYTES + 2 * C_BYTES, stream);

    wtrans_kernel<<<512, 256, 0, stream>>>(rk0, rk0, B0S, 576);
    wtrans_kernel<<<512, 256, 0, stream>>>(k1, rk1, B1S, 1152);

    float* oh0 = out;
    float* oc0 = out + (size_t)PIX * FF;
    float* oh1 = out + 2 * (size_t)PIX * FF;
    float* oc1 = out + 3 * (size_t)PIX * FF;

    // Tick u: layer-0 computes step u (reads h0[u-1] -> writes h0[u]);
    //         layer-1 computes step u-1 (reads h0[u-1], h1[u-2] -> h1[u-1]).
    for (int u = 0; u <= T_STEPS; ++u) {
        const u16* h0_prev = h0p[(u + 1) & 1];
        u16*       h0_new  = h0p[u & 1];
        const u16* h1_prev = h1p[u & 1];
        u16*       h1_new  = h1p[(u + 1) & 1];
        fused_step_kernel<<<512, 256, 0, stream>>>(
            h0_prev, h0_new, h1_prev, h1_new, B0S, B1S,
            x, k0, b0, b1, c0, c1, oh0, oc0, oh1, oc1, u);
    }
}

// Round 5
// 492.181 us; speedup vs baseline: 1.1099x; 1.1099x over previous
//
#include <hip/hip_runtime.h>
#include <hip/hip_bf16.h>

typedef unsigned short u16;
typedef __attribute__((ext_vector_type(8))) short short8;
typedef __attribute__((ext_vector_type(4))) float f32x4;

#define T_STEPS 10
#define NB 8
#define HH 64
#define WW 64
#define FF 64
#define NGATE 256
#define HP 66
#define PIX (NB*HH*WW)          // 32768

__device__ __forceinline__ u16 f2bf(float f) {
    unsigned u = __float_as_uint(f);
    u += 0x7FFF + ((u >> 16) & 1);   // round-to-nearest-even
    return (u16)(u >> 16);
}
__device__ __forceinline__ float hsig(float x) {
    return fminf(fmaxf(0.2f * x + 0.5f, 0.0f), 1.0f);
}
__device__ __forceinline__ float ftanh(float x) {
    float e = __expf(2.0f * x);
    return 1.0f - 2.0f / (e + 1.0f);
}
__device__ __forceinline__ void gll16(const void* g, void* l) {
    __builtin_amdgcn_global_load_lds(
        (const __attribute__((address_space(1))) unsigned*)g,
        (__attribute__((address_space(3))) unsigned*)l, 16, 0, 0);
}

// Build B in MFMA-fragment-stream order, bf16:
//   stream[kc][fq][ks][g][lane][e]; value = W[kc*64+ks*32+quad*8+e][g*64+fq*16+l15]
__global__ void wtrans_kernel(const float* __restrict__ W0,
                              const float* __restrict__ W1,
                              u16* __restrict__ BS, int K) {
    int total = (K >> 6) << 14;
    for (int o = blockIdx.x * blockDim.x + threadIdx.x; o < total;
         o += gridDim.x * blockDim.x) {
        int e = o & 7, lane = (o >> 3) & 63, g = (o >> 9) & 3;
        int ks = (o >> 11) & 1, fq = (o >> 12) & 3, kc = o >> 14;
        int quad = lane >> 4, l15 = lane & 15;
        int n = g * 64 + fq * 16 + l15;
        int k = kc * 64 + ks * 32 + quad * 8 + e;
        float v = (k < 576) ? W0[k * NGATE + n] : W1[(k - 576) * NGATE + n];
        BS[o] = f2bf(v);
    }
}

// Stage one kc-chunk of the A tile (64 pixels x 64 ch) into LDS:
// 512 16B-chunks; chunk q holds px=q>>3, ch-block (q&7)^(px&7).
// All indices recomputed from tid (register diet: no persistent pxA/cbA).
// gll dst = per-thread base + q*16 == wave-uniform base + lane*16 as the
// hardware requires (q = tid and 256+tid).
__device__ __forceinline__ void stageA(const u16* __restrict__ h0_prev,
                                       const u16* __restrict__ h1_prev,
                                       int kcs, int b, int y, int tid,
                                       u16* __restrict__ lbase) {
    int tau = (kcs < 9) ? kcs : kcs - 9;
    const u16* src = (kcs < 9) ? h0_prev : h1_prev;
    int dy = tau / 3 - 1, dx = tau % 3 - 1;
    const u16* rbase = src + (((size_t)(b * HP + y + dy + 1)) * HP + dx + 1) * FF;
    int q0 = tid, q1 = 256 + tid;
    int p0 = q0 >> 3, cb0 = (q0 & 7) ^ (p0 & 7);
    int p1 = q1 >> 3, cb1 = (q1 & 7) ^ (p1 & 7);
    gll16(rbase + (size_t)p0 * FF + cb0 * 8, lbase + (size_t)q0 * 8);
    gll16(rbase + (size_t)p1 * FF + cb1 * 8, lbase + (size_t)q1 * 8);
}

// Fused dual-layer ConvLSTM tick; XCD-local batches (batch = blockIdx & 7).
// M=64 (1 image row / block), 1024 blocks, 2 role-0 + 2 role-1 per CU.
// Occupancy is the binding resource (r1-r4 post-mortem: perf tracks
// waves/SIMD exactly; pool ~512 regs/SIMD unified VGPR+AGPR):
//   M=64 acc = 64 regs -> target <=~135 total -> 3-4 waves/SIMD.
// So: NO register B ping-pong (costs 64 regs = one occupancy step),
// bF loaded at use; staging indices recomputed in stageA; r0's proven
// triple-buffer gll pipeline with vmcnt(2) barriers; setprio around MFMA
// (reg-free; 3-4 waves/SIMD at different phases to arbitrate).
__global__ __launch_bounds__(256, 4)
void fused_step_kernel(const u16* __restrict__ h0_prev, u16* __restrict__ h0_new,
                       const u16* __restrict__ h1_prev, u16* __restrict__ h1_new,
                       const u16* __restrict__ B0S, const u16* __restrict__ B1S,
                       const float* __restrict__ x, const float* __restrict__ k0w,
                       const float* __restrict__ b0, const float* __restrict__ b1,
                       float* __restrict__ c0, float* __restrict__ c1,
                       float* __restrict__ oh0, float* __restrict__ oc0,
                       float* __restrict__ oh1, float* __restrict__ oc1,
                       int u) {
    int blk = blockIdx.x;
    int b = blk & 7;                 // batch == XCD (blockIdx % 8 round-robin)
    int k = blk >> 3;                // XCD-local index 0..127 (-> CU k%32)
    int role = (k >> 5) & 1;         // balanced: every CU 2 role-0 + 2 role-1
    int y = (k & 31) | ((k >> 6) << 5);   // image row 0..63
    int pxb = b * 64 + y;
    if (role == 0 && u >= T_STEPS) return;
    if (role == 1 && u == 0) return;

    __shared__ __align__(16) u16 sA3[3][4096];
    __shared__ float xs[3][WW + 2];

    int tid = threadIdx.x;
    int lane = tid & 63, fq = tid >> 6;
    int quad = lane >> 4, l15 = lane & 15;

    const u16* BS = role ? B1S : B0S;
    int nch = role ? 18 : 9;

    if (role == 0 && tid < 3 * (WW + 2)) {
        int dyi = tid / (WW + 2), xx = tid - dyi * (WW + 2);
        int yy = y + dyi - 1, col = xx - 1;
        float v = 0.0f;
        if (yy >= 0 && yy < HH && col >= 0 && col < WW)
            v = x[(((size_t)b * T_STEPS + u) * HH + yy) * WW + col];
        xs[dyi][xx] = v;
    }

    f32x4 acc[4][4];
#pragma unroll
    for (int mt = 0; mt < 4; ++mt)
#pragma unroll
        for (int g = 0; g < 4; ++g)
            acc[mt][g] = (f32x4){0.f, 0.f, 0.f, 0.f};

    // ---- pipeline prologue ----
    stageA(h0_prev, h1_prev, 0, b, y, tid, &sA3[0][0]);
    asm volatile("s_waitcnt vmcnt(0) lgkmcnt(0)\n\ts_barrier" ::: "memory");
    if (nch > 1)
        stageA(h0_prev, h1_prev, 1, b, y, tid, &sA3[1][0]);

    int sx = l15 & 7;
    int cur = 0;
    for (int kc = 0; kc < nch; ++kc) {
        // compute on buffer cur (gll(kc) drained by previous barrier)
#pragma unroll
        for (int ks = 0; ks < 2; ++ks) {
            short8 bF[4];
            const u16* bp = BS + (((size_t)kc << 14) | (fq << 12) | (ks << 11))
                          + lane * 8;
#pragma unroll
            for (int g = 0; g < 4; ++g)
                bF[g] = *(const short8*)(bp + ((size_t)g << 9));
            short8 aF[4];
#pragma unroll
            for (int mt = 0; mt < 4; ++mt) {
                int px = mt * 16 + l15;
                int chunk = px * 8 + ((ks * 4 + quad) ^ sx);
                aF[mt] = *(const short8*)&sA3[cur][(size_t)chunk * 8];
            }
            __builtin_amdgcn_s_setprio(1);
#pragma unroll
            for (int mt = 0; mt < 4; ++mt)
#pragma unroll
                for (int g = 0; g < 4; ++g)
                    acc[mt][g] = __builtin_amdgcn_mfma_f32_16x16x32_bf16(
                        aF[mt], bF[g], acc[mt][g], 0, 0, 0);
            __builtin_amdgcn_s_setprio(0);
        }
        // distance-2 prefetch; dummy re-stage of an unread buffer in the tail
        // keeps the per-iteration vmcnt count uniform (always 2 glls issued).
        {
            int ksrc = (kc + 2 < nch) ? kc + 2 : kc;
            int bdst = (cur + 2 >= 3) ? cur - 1 : cur + 2;
            stageA(h0_prev, h1_prev, ksrc, b, y, tid, &sA3[bdst][0]);
        }
        // drain gll(kc+1) (+ all B loads); keep gll(kc+2) in flight.
        asm volatile("s_waitcnt vmcnt(2) lgkmcnt(0)\n\ts_barrier" ::: "memory");
        cur = (cur == 2) ? 0 : cur + 1;
    }

    // ---- epilogue: LSTM gate update (lane-local: f = fq*16+l15) ----
    const float* bias = role ? b1 : b0;
    float* cbuf = role ? c1 : c0;
    u16* hout = role ? h1_new : h0_new;
    int wo = role ? (u == T_STEPS) : (u == T_STEPS - 1);
    float* outh = role ? oh1 : oh0;
    float* outc = role ? oc1 : oc0;

    int f = fq * 16 + l15;
    float bi = bias[f], bff = bias[64 + f], bg = bias[128 + f], bo = bias[192 + f];
    float wk[4][9];
    if (role == 0) {
#pragma unroll
        for (int g = 0; g < 4; ++g)
#pragma unroll
            for (int tau = 0; tau < 9; ++tau)
                wk[g][tau] = k0w[tau * NGATE + g * 64 + f];
    }
#pragma unroll
    for (int mt = 0; mt < 4; ++mt) {
#pragma unroll
        for (int r = 0; r < 4; ++r) {
            int xcol = mt * 16 + quad * 4 + r;      // pixel x within the row
            size_t p = (size_t)pxb * 64 + xcol;     // global pixel
            float zi = acc[mt][0][r] + bi;
            float zf = acc[mt][1][r] + bff;
            float zg = acc[mt][2][r] + bg;
            float zo = acc[mt][3][r] + bo;
            if (role == 0) {   // fused layer-0 input conv, fp32 exact
#pragma unroll
                for (int tau = 0; tau < 9; ++tau) {
                    float xv = xs[tau / 3][xcol + tau % 3];
                    zi += xv * wk[0][tau];
                    zf += xv * wk[1][tau];
                    zg += xv * wk[2][tau];
                    zo += xv * wk[3][tau];
                }
            }
            float cold = cbuf[p * FF + f];
            float cn = hsig(zf) * cold + hsig(zi) * ftanh(zg);
            float hn = hsig(zo) * ftanh(cn);
            cbuf[p * FF + f] = cn;
            hout[(((size_t)(b * HP + y + 1)) * HP + (xcol + 1)) * FF + f] = f2bf(hn);
            if (wo) { outh[p * FF + f] = hn; outc[p * FF + f] = cn; }
        }
    }
}

extern "C" void kernel_launch(void* const* d_in, const int* in_sizes, int n_in,
                              void* d_out, int out_size, void* d_ws, size_t ws_size,
                              hipStream_t stream) {
    const float* x   = (const float*)d_in[0];
    const float* k0  = (const float*)d_in[1];
    const float* rk0 = (const float*)d_in[2];
    const float* b0  = (const float*)d_in[3];
    const float* k1  = (const float*)d_in[4];
    const float* rk1 = (const float*)d_in[5];
    const float* b1  = (const float*)d_in[6];
    float* out = (float*)d_out;

    char* ws = (char*)d_ws;
    const size_t HPAD_BYTES = (size_t)NB * HP * HP * FF * 2;  // 4,460,544
    const size_t C_BYTES    = (size_t)PIX * FF * 4;           // 8,388,608

    u16* h0p[2]; u16* h1p[2];
    h0p[0] = (u16*)(ws);
    h0p[1] = (u16*)(ws + HPAD_BYTES);
    h1p[0] = (u16*)(ws + 2 * HPAD_BYTES);
    h1p[1] = (u16*)(ws + 3 * HPAD_BYTES);
    float* c0 = (float*)(ws + 4 * HPAD_BYTES);
    float* c1 = (float*)(ws + 4 * HPAD_BYTES + C_BYTES);
    u16* B0S  = (u16*)(ws + 4 * HPAD_BYTES + 2 * C_BYTES);
    u16* B1S  = (u16*)(ws + 4 * HPAD_BYTES + 2 * C_BYTES + (size_t)9 * 16384 * 2);

    // Zero h (incl. halo == SAME padding) and c states; ws is poisoned 0xAA.
    hipMemsetAsync(ws, 0, 4 * HPAD_BYTES + 2 * C_BYTES, stream);

    wtrans_kernel<<<512, 256, 0, stream>>>(rk0, rk0, B0S, 576);
    wtrans_kernel<<<512, 256, 0, stream>>>(k1, rk1, B1S, 1152);

    float* oh0 = out;
    float* oc0 = out + (size_t)PIX * FF;
    float* oh1 = out + 2 * (size_t)PIX * FF;
    float* oc1 = out + 3 * (size_t)PIX * FF;

    // Tick u: layer-0 computes step u (reads h0[u-1] -> writes h0[u]);
    //         layer-1 computes step u-1 (reads h0[u-1], h1[u-2] -> h1[u-1]).
    for (int u = 0; u <= T_STEPS; ++u) {
        const u16* h0_prev = h0p[(u + 1) & 1];
        u16*       h0_new  = h0p[u & 1];
        const u16* h1_prev = h1p[u & 1];
        u16*       h1_new  = h1p[(u + 1) & 1];
        fused_step_kernel<<<1024, 256, 0, stream>>>(
            h0_prev, h0_new, h1_prev, h1_new, B0S, B1S,
            x, k0, b0, b1, c0, c1, oh0, oc0, oh1, oc1, u);
    }
}